// Round 2
// baseline (114.745 us; speedup 1.0000x reference)
//
#include <hip/hip_runtime.h>
#include <hip/hip_bf16.h>

#define BB 4
#define NN 256
#define KK 32
#define DD 32
#define HH 8
#define NROWS 1024            // proj rows per slice: e = 1..1024 stored at e-1
#define NPTS (BB * NN * NN)   // 262144
#define NNSQ (NN * NN)        // 65536

typedef __attribute__((ext_vector_type(8))) unsigned short ushort8;

__device__ __forceinline__ unsigned short f2bf(float f) {
    unsigned u = __float_as_uint(f);
    unsigned r = (u + 0x7FFFu + ((u >> 16) & 1u)) >> 16;
    return (unsigned short)r;
}

__device__ __forceinline__ void gload16(const void* g, void* l) {
    __builtin_amdgcn_global_load_lds(
        (const __attribute__((address_space(1))) void*)g,
        (__attribute__((address_space(3))) void*)l,
        16, 0, 0);
}

// ---------------------------------------------------------------------------
// Kernel A: proj[k][e-1][h] = sum_d feat[e][d] * W[k][d][h]   (bf16, e=1..1024)
// ---------------------------------------------------------------------------
__global__ __launch_bounds__(256) void build_proj_bf16(
    const float* __restrict__ feat,   // [1025][32]
    const float* __restrict__ w,      // [32][256] (d*8+h)
    unsigned short* __restrict__ proj) // [32][1024][8]
{
    int t  = blockIdx.x * 256 + threadIdx.x;  // 0..32767
    int k  = t >> 10;                         // uniform per block
    int er = t & 1023;
    int e  = er + 1;

    const float* frow = feat + (size_t)e * DD;
    const float* wrow = w + (size_t)k * DD * HH;

    float acc[HH];
#pragma unroll
    for (int h = 0; h < HH; ++h) acc[h] = 0.0f;

#pragma unroll
    for (int d = 0; d < DD; ++d) {
        float f = frow[d];
#pragma unroll
        for (int h = 0; h < HH; ++h) acc[h] = fmaf(f, wrow[d * HH + h], acc[h]);
    }

    ushort8 o;
#pragma unroll
    for (int h = 0; h < HH; ++h) o[h] = f2bf(acc[h]);
    *(ushort8*)(proj + (size_t)t * HH) = o;
}

// ---------------------------------------------------------------------------
// Kernel B: main.  1024 threads = 1024 points per block, 256 blocks (1/CU).
// k-loop with 3-deep LDS ring of 16KB bf16 proj slices (global_load_lds,
// counted vmcnt), coalesced index loads redistributed via swizzled LDS.
// E = ints per index element (2 = int64 input, 1 = int32 input).
// ---------------------------------------------------------------------------
template <int E>
__global__ __launch_bounds__(1024, 4) void attn_bias_lds(
    const int* __restrict__ sp,       // [NPTS] (*E)
    const int* __restrict__ ei,       // [NPTS*32] (*E)
    const float* __restrict__ semb,   // [512][8]
    const unsigned short* __restrict__ proj, // [32][1024][8] bf16
    float* __restrict__ out)          // [BB][HH][NNSQ]
{
    constexpr int KPG = 16 / E;    // k's per 64B-per-point group: E=2 -> 8, E=1 -> 16
    constexpr int NG  = 32 / KPG;  // groups: 4 or 2

    __shared__ __align__(16) unsigned short tbuf[3][NROWS * HH]; // 3 x 16KB
    __shared__ int ibuf[KPG][1024];                              // 32KB / 64KB

    const int tid = threadIdx.x;
    const int p   = blockIdx.x * 1024 + tid;

    const int4* EI4 = (const int4*)ei;
    // per-point index row = 32*E ints = 8E int4; group g = 4 int4 at offset g*4
    const size_t blk_i4 = (size_t)blockIdx.x * 1024 * (8 * E);

    int4 br[4];

    // load one group's indices for all 1024 points, fully line-coalesced
    auto load_batch = [&](int g) {
#pragma unroll
        for (int c = 0; c < 4; ++c) {
            int j     = c * 1024 + tid;
            int pt    = j >> 2;
            int piece = tid & 3;
            br[c] = EI4[blk_i4 + (size_t)pt * (8 * E) + g * 4 + piece];
        }
    };

    // scatter the batch into ibuf with XOR bank swizzle
    auto publish = [&]() {
#pragma unroll
        for (int c = 0; c < 4; ++c) {
            int j     = c * 1024 + tid;
            int pt    = j >> 2;
            int piece = tid & 3;
            if (E == 2) {
                int k0 = piece * 2;
                ibuf[k0    ][pt ^ ((k0    ) << 2)] = br[c].x;
                ibuf[k0 + 1][pt ^ ((k0 + 1) << 2)] = br[c].z;
            } else {
                int k0 = piece * 4;
                ibuf[k0    ][pt ^ ((k0    ) << 2)] = br[c].x;
                ibuf[k0 + 1][pt ^ ((k0 + 1) << 2)] = br[c].y;
                ibuf[k0 + 2][pt ^ ((k0 + 2) << 2)] = br[c].z;
                ibuf[k0 + 3][pt ^ ((k0 + 3) << 2)] = br[c].w;
            }
        }
    };

    auto stage = [&](int k, int slot) {
        gload16(proj + (size_t)k * (NROWS * HH) + tid * 8, &tbuf[slot][tid * 8]);
    };

    // ---------------- prologue ----------------
    load_batch(0);
    stage(0, 0);
    stage(1, 1);

    int s = (E == 2) ? ((const int2*)sp)[p].x : sp[p];
    const float4* srow = (const float4*)(semb + (size_t)s * HH);
    float4 s0 = srow[0], s1 = srow[1];
    float sb[HH] = {s0.x, s0.y, s0.z, s0.w, s1.x, s1.y, s1.z, s1.w};

    publish();
    __syncthreads();   // full drain: stages 0/1 + batch0 + spatial all complete

    float acc[HH];
#pragma unroll
    for (int h = 0; h < HH; ++h) acc[h] = 0.0f;
    int cnt = 0;
    int eg[KPG];

    // ---------------- main k loop (fully unrolled) ----------------
#pragma unroll
    for (int k = 0; k < 32; ++k) {
        const int gq = k / KPG;
        const int kq = k % KPG;

        if (k > 0) {
            // counted vmcnt: batch (4 loads) issued at group start sits between
            // stage(gs+2) and stage(gs+3) in FIFO order -> bulge of 5 at gs+1,gs+2
            const bool bulge = (kq == 1 || kq == 2) && (gq <= NG - 2);
            if (k == 31)     asm volatile("s_waitcnt vmcnt(0)" ::: "memory");
            else if (bulge)  asm volatile("s_waitcnt vmcnt(5)" ::: "memory");
            else             asm volatile("s_waitcnt vmcnt(1)" ::: "memory");
            __builtin_amdgcn_s_barrier();
            if (kq == 0) {   // group boundary: publish batch loaded KPG iters ago
                publish();
                asm volatile("s_waitcnt lgkmcnt(0)" ::: "memory");
                __builtin_amdgcn_s_barrier();
            }
        }

        if (k < 30) stage(k + 2, (k + 2) % 3);
        asm volatile("" ::: "memory");  // keep stage before batch loads in VMEM FIFO
        if (kq == 0 && gq <= NG - 2) load_batch(gq + 1);

        if (kq == 0) {   // fetch this group's indices for my point
#pragma unroll
            for (int q = 0; q < KPG; ++q) eg[q] = ibuf[q][tid ^ (q << 2)];
        }

        // compute hop k
        int   e = eg[kq];
        int   r = (e > 0) ? (e - 1) : 0;       // e==0 -> row 0, masked by m
        float m = (e != 0) ? 1.0f : 0.0f;
        cnt += (e != 0);
        ushort8 row = *(const ushort8*)&tbuf[k % 3][r * HH];
#pragma unroll
        for (int h = 0; h < HH; ++h)
            acc[h] = fmaf(m, __uint_as_float(((unsigned)row[h]) << 16), acc[h]);
    }

    // ---------------- epilogue ----------------
    float inv = 1.0f / (float)(cnt ? cnt : 1);
    const int bout = p >> 16;
    const int rr   = p & (NNSQ - 1);
    float* o = out + (size_t)bout * (HH * NNSQ) + rr;
#pragma unroll
    for (int h = 0; h < HH; ++h)
        o[(size_t)h * NNSQ] = sb[h] + acc[h] * inv;
}

extern "C" void kernel_launch(void* const* d_in, const int* in_sizes, int n_in,
                              void* d_out, int out_size, void* d_ws, size_t ws_size,
                              hipStream_t stream) {
    const int*   sp = (const int*)d_in[0];    // spatial_pos  [4,256,256]
    const int*   ei = (const int*)d_in[1];    // edge_input   [4,256,256,32]
    const float* se = (const float*)d_in[2];  // spatial_emb  [512,8]
    const float* fe = (const float*)d_in[3];  // edge_feat_emb[1025,32]
    const float* pw = (const float*)d_in[4];  // edge_pos_emb [32,256]
    float* out = (float*)d_out;

    const bool i64 = (in_sizes[0] == 2 * NPTS);
    unsigned short* proj = (unsigned short*)d_ws;   // 32*1024*8*2 = 512KB

    build_proj_bf16<<<128, 256, 0, stream>>>(fe, pw, proj);

    if (i64) attn_bias_lds<2><<<256, 1024, 0, stream>>>(sp, ei, se, proj, out);
    else     attn_bias_lds<1><<<256, 1024, 0, stream>>>(sp, ei, se, proj, out);
}